// Round 4
// baseline (1893.266 us; speedup 1.0000x reference)
//
#include <hip/hip_runtime.h>

// ParallelExperts MoE, fused token-major, software-pipelined, 8-wave blocks.
// out[t] = gates[t,0]*x[t]@W[e(2t)]^T + gates[t,1]*x[t]@W[e(2t+1)]^T
// N=262144, k=2, E=8, D=128.
//
// prep_kernel: inv[ssi[p]] = sei[p] (slot->expert byte) + weights fp32->f16.
// moe_fused_kernel: 512 persistent blocks x 512 threads, TILES=8 tiles of
//   64 tokens. Per tile: regs->LDS A-tile (f16), wave-0 ballot counting-sort,
//   run-masked MFMA 16x16x32_f16 (each wave: 64 rows x 32 cols => acc=32
//   VGPR), g*y staged in LDS, coalesced f32 out. Tile i+1 prefetched into
//   regs AFTER the MFMA loop (vmcnt is FIFO: bf waits must not include the
//   prefetch). Barriers are s_barrier + lgkmcnt(0) only -- global loads and
//   stores stay in flight across phase boundaries.
// Round-3 lesson: 256-thread version spilled (acc64+bf32+xr32 > 128 VGPR
//   budget) -> scratch thrash to HBM (FETCH+WRITE tripled). 8-wave split
//   halves acc and xr; peak live ~100 VGPR.

#define D       128
#define TB      64       // tokens per tile
#define SLOTS   128      // slots per tile (k=2)
#define LSTR    136      // LDS row stride in f16 (272 B, 16B-aligned rows)
#define NTOK    262144
#define NK      (NTOK * 2)
#define NEXP    8
#define TPB     512
#define TILES   8
#define GRID    (NTOK / (TB * TILES))   // 512 = 2 blocks/CU x 256 CUs

typedef _Float16 halfx8 __attribute__((ext_vector_type(8)));
typedef _Float16 halfx4 __attribute__((ext_vector_type(4)));
typedef _Float16 halfx2 __attribute__((ext_vector_type(2)));
typedef float    floatx4 __attribute__((ext_vector_type(4)));

// LDS-visibility barrier that does NOT drain vmcnt: outstanding global
// loads (prefetch) and stores (epilogue) stay in flight across it.
__device__ __forceinline__ void barrier_lds()
{
    asm volatile("s_waitcnt lgkmcnt(0)" ::: "memory");
    __builtin_amdgcn_s_barrier();
}

// blocks [0, 2048): inv[ssi[p]] = sei[p]   (slot -> expert id, 1 byte)
// blocks [2048, 2176): weight fp32 -> f16  (8*128*128 = 131072 elements)
__global__ __launch_bounds__(256)
void prep_kernel(const int* __restrict__ sei, const int* __restrict__ ssi,
                 const float* __restrict__ weight,
                 unsigned char* __restrict__ inv, _Float16* __restrict__ wh)
{
    const int b = blockIdx.x, tid = threadIdx.x;
    if (b < NK / 256) {
        const int p = b * 256 + tid;
        inv[ssi[p]] = (unsigned char)sei[p];
    } else {
        const int i = ((b - NK / 256) * 256 + tid) * 4;
        float4 v = *(const float4*)(weight + i);
        halfx4 h = { (_Float16)v.x, (_Float16)v.y, (_Float16)v.z, (_Float16)v.w };
        *(halfx4*)(wh + i) = h;
    }
}

__global__ __launch_bounds__(512, 4)
void moe_fused_kernel(const float* __restrict__ inputs,
                      const _Float16* __restrict__ wh,
                      const float* __restrict__ gates,
                      const unsigned char* __restrict__ inv,
                      float* __restrict__ out)
{
    // Rows 0..63: A-tile (tokens, f16). After MFMA the whole buffer is
    // reused as Y (128 sorted slot rows of g*y). Same stride.
    __shared__ _Float16 As[SLOTS * LSTR];
    __shared__ int   atok[SLOTS];    // sorted pos -> local token
    __shared__ int   posOf[SLOTS];   // local slot -> sorted pos
    __shared__ float gs[SLOTS];      // sorted pos -> gate
    __shared__ int   ebase[NEXP + 1];

    const int tid  = threadIdx.x;
    const int lane = tid & 63;
    const int w    = tid >> 6;       // wave 0..7
    const int m    = lane & 15;
    const int q    = lane >> 4;
    const int R0   = (w >> 2) * 64;  // wave's sorted-row base (0 or 64)
    const int c0   = (w & 3) * 32;   // wave's output-column base

    const int tile0 = blockIdx.x * TILES;

    float4 xr[4];                    // prefetched input rows (16 regs)
    int   myE0 = 0, myE1 = 0;        // wave-0 only
    float myG0 = 0.f, myG1 = 0.f;

    // ---- prologue: issue loads for tile 0 ----
    {
        const int t0 = tile0 * TB;
        #pragma unroll
        for (int it = 0; it < 4; ++it) {
            const int id = it * TPB + tid;
            xr[it] = ((const float4*)inputs)[((size_t)t0 + (id >> 5)) * 32 + (id & 31)];
        }
        if (w == 0) {
            myE0 = inv[(size_t)t0 * 2 + lane];
            myE1 = inv[(size_t)t0 * 2 + 64 + lane];
            myG0 = gates[(size_t)t0 * 2 + lane];
            myG1 = gates[(size_t)t0 * 2 + 64 + lane];
        }
    }

    #pragma unroll 1
    for (int i = 0; i < TILES; ++i) {
        const int t0 = (tile0 + i) * TB;

        if (i) barrier_lds();                    // B1: prev epilogue LDS reads done

        // ---- phase S: A-store (all waves) + wave-0 ballot sort ----
        #pragma unroll
        for (int it = 0; it < 4; ++it) {
            const int id = it * TPB + tid;
            const int r = id >> 5, c4 = id & 31;
            float4 v = xr[it];
            halfx4 h = { (_Float16)v.x, (_Float16)v.y, (_Float16)v.z, (_Float16)v.w };
            *(halfx4*)&As[r * LSTR + c4 * 4] = h;
        }
        if (w == 0) {
            const unsigned long long lt =
                lane ? (~0ull >> (64 - lane)) : 0ull;
            int r0 = 0, r1 = 0, run = 0;
            #pragma unroll
            for (int e = 0; e < NEXP; ++e) {
                unsigned long long b0 = __ballot(myE0 == e);
                unsigned long long b1 = __ballot(myE1 == e);
                const int n0 = __popcll(b0), n1 = __popcll(b1);
                if (lane == 0) ebase[e] = run;
                if (myE0 == e) r0 = run + __popcll(b0 & lt);
                if (myE1 == e) r1 = run + n0 + __popcll(b1 & lt);
                run += n0 + n1;
            }
            if (lane == 0) ebase[NEXP] = run;    // == SLOTS
            posOf[lane]      = r0;
            posOf[lane + 64] = r1;
            atok[r0] = lane >> 1;                // k == 2
            atok[r1] = (lane + 64) >> 1;
            gs[r0] = myG0;
            gs[r1] = myG1;
        }
        barrier_lds();                           // B2: A + sort tables ready

        // ---- MFMA over per-expert runs (wave: rows R0..R0+63, cols c0..) ----
        int aoff[4];
        #pragma unroll
        for (int rt = 0; rt < 4; ++rt) aoff[rt] = atok[R0 + rt * 16 + m] * LSTR;

        floatx4 acc[4][2];
        #pragma unroll
        for (int rt = 0; rt < 4; ++rt) {
            acc[rt][0] = {0.f, 0.f, 0.f, 0.f};
            acc[rt][1] = {0.f, 0.f, 0.f, 0.f};
        }

        for (int e = 0; e < NEXP; ++e) {
            const int s0 = ebase[e], s1 = ebase[e + 1];
            if (s0 == s1) continue;              // empty run
            if (s1 <= R0 || s0 >= R0 + 64) continue;   // outside wave's rows

            halfx8 bf[2][4];
            #pragma unroll
            for (int ct = 0; ct < 2; ++ct) {
                const _Float16* wrow = wh + (size_t)e * (D * D)
                                          + (size_t)(c0 + 2 * m + ct) * D;
                #pragma unroll
                for (int ks = 0; ks < 4; ++ks)
                    bf[ct][ks] = *(const halfx8*)(wrow + ks * 32 + q * 8);
            }

            const int a0 = (s0 > R0) ? (s0 - R0) : 0;          // 0..63
            const int a1 = (s1 < R0 + 64) ? (s1 - R0) : 64;    // a1 > a0
            const int rt_lo = a0 >> 4, rt_hi = (a1 - 1) >> 4;
            #pragma unroll
            for (int rt = 0; rt < 4; ++rt) {     // static acc indexing
                if (rt < rt_lo || rt > rt_hi) continue;
                const int row = R0 + rt * 16 + m;
                const bool in = (row >= s0) && (row < s1);
                #pragma unroll
                for (int ks = 0; ks < 4; ++ks) {
                    const int kk = ks * 32 + q * 8;
                    halfx8 a = {0, 0, 0, 0, 0, 0, 0, 0};
                    if (in) a = *(const halfx8*)&As[aoff[rt] + kk];
                    acc[rt][0] = __builtin_amdgcn_mfma_f32_16x16x32_f16(a, bf[0][ks], acc[rt][0], 0, 0, 0);
                    acc[rt][1] = __builtin_amdgcn_mfma_f32_16x16x32_f16(a, bf[1][ks], acc[rt][1], 0, 0, 0);
                }
            }
        }

        // ---- prefetch tile i+1 (issued after bf loads; in flight across
        //      B3/B4/B1, consumed in next tile's phase S) ----
        if (i + 1 < TILES) {
            const int t0n = (tile0 + i + 1) * TB;
            #pragma unroll
            for (int it = 0; it < 4; ++it) {
                const int id = it * TPB + tid;
                xr[it] = ((const float4*)inputs)[((size_t)t0n + (id >> 5)) * 32 + (id & 31)];
            }
            if (w == 0) {
                myE0 = inv[(size_t)t0n * 2 + lane];
                myE1 = inv[(size_t)t0n * 2 + 64 + lane];
                myG0 = gates[(size_t)t0n * 2 + lane];
                myG1 = gates[(size_t)t0n * 2 + 64 + lane];
            }
        }

        barrier_lds();                           // B3: all A-reads done, As reusable
        _Float16* Y = As;

        // ---- stage g*y: sorted row = R0 + rt*16 + q*4 + r; cols c0+2m(+1) ----
        #pragma unroll
        for (int rt = 0; rt < 4; ++rt) {
            #pragma unroll
            for (int r = 0; r < 4; ++r) {
                const int row = R0 + rt * 16 + q * 4 + r;
                const float g = gs[row];
                halfx2 h = { (_Float16)(acc[rt][0][r] * g),
                             (_Float16)(acc[rt][1][r] * g) };
                *(halfx2*)&Y[row * LSTR + c0 + 2 * m] = h;
            }
        }
        barrier_lds();                           // B4: Y ready

        // ---- combine both slots of each token, coalesced f32 out ----
        #pragma unroll
        for (int it = 0; it < 2; ++it) {
            const int idx = it * TPB + tid;      // 0..1023
            const int r   = idx >> 4;            // token row 0..63
            const int c8  = (idx & 15) * 8;      // f32 col 0..120
            const int p0  = posOf[2 * r];
            const int p1  = posOf[2 * r + 1];
            halfx8 a = *(const halfx8*)&Y[p0 * LSTR + c8];
            halfx8 b = *(const halfx8*)&Y[p1 * LSTR + c8];
            float* dst = out + (size_t)(t0 + r) * D + c8;
            floatx4 lo = { (float)a[0] + (float)b[0], (float)a[1] + (float)b[1],
                           (float)a[2] + (float)b[2], (float)a[3] + (float)b[3] };
            floatx4 hi = { (float)a[4] + (float)b[4], (float)a[5] + (float)b[5],
                           (float)a[6] + (float)b[6], (float)a[7] + (float)b[7] };
            __builtin_nontemporal_store(lo, (floatx4*)dst);
            __builtin_nontemporal_store(hi, (floatx4*)(dst + 4));
        }
    }
}

extern "C" void kernel_launch(void* const* d_in, const int* in_sizes, int n_in,
                              void* d_out, int out_size, void* d_ws, size_t ws_size,
                              hipStream_t stream)
{
    const float* inputs = (const float*)d_in[0];   // [N, 128] fp32
    const float* weight = (const float*)d_in[1];   // [8, 128, 128] fp32
    const float* gates  = (const float*)d_in[2];   // [N, 2] fp32
    const int*   sei    = (const int*)d_in[4];     // sorted_expert_idxs [N*2]
    const int*   ssi    = (const int*)d_in[5];     // sorted_scattered_idxs [N*2]
    float* out = (float*)d_out;

    unsigned char* inv = (unsigned char*)d_ws;                 // NK bytes
    _Float16*      wh  = (_Float16*)((char*)d_ws + NK);        // 256 KB f16 weights

    prep_kernel<<<dim3(NK / 256 + (NEXP * D * D) / 1024), dim3(256), 0, stream>>>(
        sei, ssi, weight, inv, wh);

    moe_fused_kernel<<<dim3(GRID), dim3(TPB), 0, stream>>>(
        inputs, wh, gates, inv, out);
}

// Round 5
// 333.080 us; speedup vs baseline: 5.6841x; 5.6841x over previous
//
#include <hip/hip_runtime.h>

// ParallelExperts MoE, fused token-major. Minimal-risk variant:
// R1's verified skeleton (256 threads, 1 tile/block, __syncthreads, plain
// stores, clean byte counts) with ONE change: the LDS-atomic counting sort
// + tid-0 serial prefix (+1 barrier) is replaced by a wave-0 ballot
// counting sort (verified in r3/r4). A-gather is direct/contiguous.
// Round-3/4 lesson: persistent+prefetch structures made hipcc spill to
// scratch (WRITE_SIZE 5.3 GB, W>>R = spill writebacks); stay with the
// byte-clean structure.
//
// out[t] = gates[t,0]*x[t]@W[e(2t)]^T + gates[t,1]*x[t]@W[e(2t+1)]^T
// N=262144, k=2, E=8, D=128.

#define D       128
#define TB      64       // tokens per block
#define SLOTS   128      // slots per block (k=2)
#define LSTR    136      // LDS row stride in f16 (272 B, 16B-aligned rows)
#define NTOK    262144
#define NK      (NTOK * 2)
#define NEXP    8

typedef _Float16 halfx8 __attribute__((ext_vector_type(8)));
typedef _Float16 halfx4 __attribute__((ext_vector_type(4)));
typedef _Float16 halfx2 __attribute__((ext_vector_type(2)));
typedef float    floatx4 __attribute__((ext_vector_type(4)));

// blocks [0, 2048): inv[ssi[p]] = sei[p]   (slot -> expert id, 1 byte)
// blocks [2048, 2176): weight fp32 -> f16  (8*128*128 = 131072 elements)
__global__ __launch_bounds__(256)
void prep_kernel(const int* __restrict__ sei, const int* __restrict__ ssi,
                 const float* __restrict__ weight,
                 unsigned char* __restrict__ inv, _Float16* __restrict__ wh)
{
    const int b = blockIdx.x, tid = threadIdx.x;
    if (b < NK / 256) {
        const int p = b * 256 + tid;
        inv[ssi[p]] = (unsigned char)sei[p];
    } else {
        const int i = ((b - NK / 256) * 256 + tid) * 4;
        float4 v = *(const float4*)(weight + i);
        halfx4 h = { (_Float16)v.x, (_Float16)v.y, (_Float16)v.z, (_Float16)v.w };
        *(halfx4*)(wh + i) = h;
    }
}

__global__ __launch_bounds__(256, 4)
void moe_fused_kernel(const float* __restrict__ inputs,
                      const _Float16* __restrict__ wh,
                      const float* __restrict__ gates,
                      const unsigned char* __restrict__ inv,
                      float* __restrict__ out)
{
    // Rows 0..63 hold the A-tile (tokens, f16); after MFMA the whole buffer
    // is reused as Y (128 sorted slot rows of g*y, f16). Same stride.
    __shared__ _Float16 As[SLOTS * LSTR];
    __shared__ int   atok[SLOTS];    // sorted pos -> local token
    __shared__ int   posOf[SLOTS];   // local slot -> sorted pos
    __shared__ float gs[SLOTS];      // sorted pos -> gate
    __shared__ int   ebase[NEXP + 1];

    const int tid  = threadIdx.x;
    const int lane = tid & 63;
    const int w    = tid >> 6;       // wave 0..3
    const int m    = lane & 15;
    const int q    = lane >> 4;
    const int c0   = w * 32;         // wave's output-column base

    const int t0 = blockIdx.x * TB;

    // ---- wave 0: slot metadata (2 slots/lane); hides under the A-gather ----
    int myE0 = 0, myE1 = 0; float myG0 = 0.f, myG1 = 0.f;
    if (w == 0) {
        myE0 = inv[(size_t)t0 * 2 + lane];
        myE1 = inv[(size_t)t0 * 2 + 64 + lane];
        myG0 = gates[(size_t)t0 * 2 + lane];
        myG1 = gates[(size_t)t0 * 2 + 64 + lane];
    }

    // ---- stage 64 token rows, direct & fully coalesced, fp32 -> f16 ----
    #pragma unroll
    for (int it = 0; it < 8; ++it) {
        const int id = it * 256 + tid;        // 0..2047 float4 slots
        const int r  = id >> 5;               // token row 0..63
        const int c4 = id & 31;               // float4 column
        float4 v = ((const float4*)inputs)[((size_t)t0 + r) * 32 + c4];
        halfx4 h = { (_Float16)v.x, (_Float16)v.y, (_Float16)v.z, (_Float16)v.w };
        *(halfx4*)&As[r * LSTR + c4 * 4] = h;
    }

    // ---- wave-0 ballot counting sort (no atomics, no serial prefix) ----
    if (w == 0) {
        const unsigned long long lt = lane ? (~0ull >> (64 - lane)) : 0ull;
        int r0 = 0, r1 = 0, run = 0;
        #pragma unroll
        for (int e = 0; e < NEXP; ++e) {
            unsigned long long b0 = __ballot(myE0 == e);
            unsigned long long b1 = __ballot(myE1 == e);
            const int n0 = __popcll(b0), n1 = __popcll(b1);
            if (lane == 0) ebase[e] = run;
            if (myE0 == e) r0 = run + __popcll(b0 & lt);
            if (myE1 == e) r1 = run + n0 + __popcll(b1 & lt);
            run += n0 + n1;
        }
        if (lane == 0) ebase[NEXP] = run;     // == SLOTS
        posOf[lane]      = r0;
        posOf[lane + 64] = r1;
        atok[r0] = lane >> 1;                 // k == 2
        atok[r1] = (lane + 64) >> 1;
        gs[r0] = myG0;
        gs[r1] = myG1;
    }
    __syncthreads();                          // B1: A-tile + sort tables ready

    // ---- MFMA over per-expert runs (run-masked; verified in r1/r3) ----
    int aoff[8];
    #pragma unroll
    for (int rt = 0; rt < 8; ++rt) aoff[rt] = atok[rt * 16 + m] * LSTR;

    floatx4 acc[8][2];
    #pragma unroll
    for (int rt = 0; rt < 8; ++rt) {
        acc[rt][0] = {0.f, 0.f, 0.f, 0.f};
        acc[rt][1] = {0.f, 0.f, 0.f, 0.f};
    }

    for (int e = 0; e < NEXP; ++e) {
        const int s0 = ebase[e], s1 = ebase[e + 1];
        if (s0 == s1) continue;               // uniform branch, empty run

        halfx8 bf[2][4];
        #pragma unroll
        for (int ct = 0; ct < 2; ++ct) {
            const _Float16* wrow = wh + (size_t)e * (D * D)
                                      + (size_t)(c0 + 2 * m + ct) * D;
            #pragma unroll
            for (int ks = 0; ks < 4; ++ks)
                bf[ct][ks] = *(const halfx8*)(wrow + ks * 32 + q * 8);
        }

        const int rt_lo = s0 >> 4, rt_hi = (s1 - 1) >> 4;
        #pragma unroll
        for (int rt = 0; rt < 8; ++rt) {      // static acc indexing
            if (rt < rt_lo || rt > rt_hi) continue;   // uniform skip
            const int row = rt * 16 + m;
            const bool in = (row >= s0) && (row < s1);
            #pragma unroll
            for (int ks = 0; ks < 4; ++ks) {
                const int kk = ks * 32 + q * 8;
                halfx8 a = {0, 0, 0, 0, 0, 0, 0, 0};
                if (in) a = *(const halfx8*)&As[aoff[rt] + kk];
                acc[rt][0] = __builtin_amdgcn_mfma_f32_16x16x32_f16(a, bf[0][ks], acc[rt][0], 0, 0, 0);
                acc[rt][1] = __builtin_amdgcn_mfma_f32_16x16x32_f16(a, bf[1][ks], acc[rt][1], 0, 0, 0);
            }
        }
    }

    __syncthreads();                 // B2: all A reads done — safe to reuse as Y
    _Float16* Y = As;

    // ---- stage g*y: sorted row = rt*16 + q*4 + r; lane cols c0+2m(+1) ----
    #pragma unroll
    for (int rt = 0; rt < 8; ++rt) {
        #pragma unroll
        for (int r = 0; r < 4; ++r) {
            const int row = rt * 16 + q * 4 + r;
            const float g = gs[row];
            halfx2 h = { (_Float16)(acc[rt][0][r] * g),
                         (_Float16)(acc[rt][1][r] * g) };
            *(halfx2*)&Y[row * LSTR + c0 + 2 * m] = h;
        }
    }
    __syncthreads();                 // B3: Y ready

    // ---- combine both slots of each token, coalesced f32 out ----
    #pragma unroll
    for (int it = 0; it < 4; ++it) {
        const int idx = it * 256 + tid;       // 0..1023
        const int r   = idx >> 4;             // token row 0..63
        const int c8  = (idx & 15) * 8;       // f32 col 0..120
        const int p0  = posOf[2 * r];
        const int p1  = posOf[2 * r + 1];
        halfx8 a = *(const halfx8*)&Y[p0 * LSTR + c8];
        halfx8 b = *(const halfx8*)&Y[p1 * LSTR + c8];
        float* dst = out + (size_t)(t0 + r) * D + c8;
        float4 lo = { (float)a[0] + (float)b[0], (float)a[1] + (float)b[1],
                      (float)a[2] + (float)b[2], (float)a[3] + (float)b[3] };
        float4 hi = { (float)a[4] + (float)b[4], (float)a[5] + (float)b[5],
                      (float)a[6] + (float)b[6], (float)a[7] + (float)b[7] };
        *(float4*)dst = lo;
        *(float4*)(dst + 4) = hi;
    }
}

extern "C" void kernel_launch(void* const* d_in, const int* in_sizes, int n_in,
                              void* d_out, int out_size, void* d_ws, size_t ws_size,
                              hipStream_t stream)
{
    const float* inputs = (const float*)d_in[0];   // [N, 128] fp32
    const float* weight = (const float*)d_in[1];   // [8, 128, 128] fp32
    const float* gates  = (const float*)d_in[2];   // [N, 2] fp32
    const int*   sei    = (const int*)d_in[4];     // sorted_expert_idxs [N*2]
    const int*   ssi    = (const int*)d_in[5];     // sorted_scattered_idxs [N*2]
    float* out = (float*)d_out;

    unsigned char* inv = (unsigned char*)d_ws;                 // NK bytes
    _Float16*      wh  = (_Float16*)((char*)d_ws + NK);        // 256 KB f16 weights

    prep_kernel<<<dim3(NK / 256 + (NEXP * D * D) / 1024), dim3(256), 0, stream>>>(
        sei, ssi, weight, inv, wh);

    moe_fused_kernel<<<dim3(NK / SLOTS), dim3(256), 0, stream>>>(
        inputs, wh, gates, inv, out);
}